// Round 10
// baseline (912.354 us; speedup 1.0000x reference)
//
#include <hip/hip_runtime.h>
#include <hip/hip_bf16.h>
#include <cstdint>

#define N_NODES 20000
#define N_EDGES 320000
#define BATCH 8
#define HID 128
#define BH (BATCH * HID)   // 1024

typedef __attribute__((ext_vector_type(4))) float f4v;
static __device__ __forceinline__ void nt_store4(float* p, float4 v) {
    f4v t; t.x = v.x; t.y = v.y; t.z = v.z; t.w = v.w;
    __builtin_nontemporal_store(t, (f4v*)p);
}

// ---------------- workspace layout (bytes) ----------------
static constexpr size_t O_DEG  = 0;
static constexpr size_t O_CUR  = 81920;
static constexpr size_t O_OFF  = 163840;
static constexpr size_t O_DINV = 245760;
static constexpr size_t O_CSR  = 327680;    // 320000 u16 = 640,000 -> ends 967680
static constexpr size_t O_PERM = 967680;    // 20000 int -> ends 1047680
static constexpr size_t O_HIST = 1047680;   // 64 int
static constexpr size_t O_BCUR = 1047936;   // 64 int
static constexpr size_t O_HBUF = 2891776;   // 160000*128 f = 81,920,000 B

__global__ void count_deg(const int* __restrict__ col, int* __restrict__ deg) {
    int e = blockIdx.x * 256 + threadIdx.x;
    if (e < N_EDGES) atomicAdd(&deg[col[e]], 1);
}

__global__ void compute_dinv(const int* __restrict__ deg, float* __restrict__ dinv) {
    int i = blockIdx.x * 256 + threadIdx.x;
    if (i < N_NODES) {
        float d = (float)(deg[i] + 1);   // +1 self loop
        dinv[i] = 1.0f / sqrtf(d);
    }
}

__global__ __launch_bounds__(1024) void scan_offsets(const int* __restrict__ deg,
                                                     int* __restrict__ off) {
    __shared__ int part[1024];
    const int CH = 20;
    int tid = threadIdx.x;
    int base = tid * CH;
    int s = 0;
    for (int i = 0; i < CH; ++i) {
        int idx = base + i;
        if (idx < N_NODES) s += deg[idx];
    }
    part[tid] = s;
    __syncthreads();
    for (int d = 1; d < 1024; d <<= 1) {
        int add = 0;
        if (tid >= d) add = part[tid - d];
        __syncthreads();
        part[tid] += add;
        __syncthreads();
    }
    int run = part[tid] - s;
    for (int i = 0; i < CH; ++i) {
        int idx = base + i;
        if (idx < N_NODES) {
            off[idx] = run;
            run += deg[idx];
        }
    }
    if (tid == 1023) off[N_NODES] = part[1023];
}

__global__ void fill_csr(const int* __restrict__ rowi, const int* __restrict__ coli,
                         const int* __restrict__ off, int* __restrict__ cursor,
                         uint16_t* __restrict__ csr) {
    int e = blockIdx.x * 256 + threadIdx.x;
    if (e >= N_EDGES) return;
    int r = rowi[e], c = coli[e];
    int pos = atomicAdd(&cursor[c], 1);
    csr[off[c] + pos] = (uint16_t)r;
}

// Sort each node's in-edge list by src (deterministic content; locality).
__global__ __launch_bounds__(64) void sort_adj(const int* __restrict__ off,
                                               uint16_t* __restrict__ csr) {
    int n = blockIdx.x;
    int s = off[n], e = off[n + 1];
    int deg = e - s;
    if (deg <= 1 || deg > 64) return;
    int l = threadIdx.x;
    int my = (l < deg) ? (int)csr[s + l] : 0x7fffffff;
    int rank = 0;
    for (int j = 0; j < deg; ++j) {
        int kj = __shfl(my, j);
        rank += (kj < my) || (kj == my && j < l);
    }
    if (l < deg) csr[s + rank] = (uint16_t)my;
}

// ---- degree-ordered permutation (counting sort by clamped degree) ----
__global__ void deg_hist(const int* __restrict__ deg, int* __restrict__ hist) {
    int i = blockIdx.x * 256 + threadIdx.x;
    if (i < N_NODES) atomicAdd(&hist[min(deg[i], 63)], 1);
}
__global__ __launch_bounds__(64) void hist_scan(const int* __restrict__ hist,
                                                int* __restrict__ bcur) {
    int t = threadIdx.x;
    int v = hist[t];
    int sum = v;
    for (int d = 1; d < 64; d <<= 1) {
        int o = __shfl_up(sum, d);
        if (t >= d) sum += o;
    }
    bcur[t] = sum - v;   // exclusive prefix
}
__global__ void build_perm(const int* __restrict__ deg, int* __restrict__ bcur,
                           int* __restrict__ perm) {
    int i = blockIdx.x * 256 + threadIdx.x;
    if (i < N_NODES) {
        int pos = atomicAdd(&bcur[min(deg[i], 63)], 1);
        perm[pos] = i;   // values bit-identical regardless of within-bin order
    }
}

// h0[n][b][h] = concat(x[b,n,:6], fixed[n,:10]) @ W_in + b_in
__global__ __launch_bounds__(256) void input_proj(const float* __restrict__ x,
                                                  const float* __restrict__ fixedf,
                                                  const float* __restrict__ W,
                                                  const float* __restrict__ bvec,
                                                  float* __restrict__ h) {
    __shared__ float Ws[16 * HID];
    __shared__ float xs[BATCH * 6];
    __shared__ float fs[10];
    int n = blockIdx.x, tid = threadIdx.x;
    for (int i = tid; i < 16 * HID; i += 256) Ws[i] = W[i];
    if (tid < 48) {
        int b_ = tid / 6, o = tid % 6;
        xs[tid] = x[((size_t)b_ * N_NODES + n) * 6 + o];
    } else if (tid < 58) {
        fs[tid - 48] = fixedf[(size_t)n * 10 + (tid - 48)];
    }
    __syncthreads();
#pragma unroll
    for (int j = 0; j < 4; ++j) {
        int idx = tid + j * 256;
        int bb = idx >> 7, hh = idx & 127;
        float acc = bvec[hh];
#pragma unroll
        for (int k = 0; k < 6; ++k) acc += xs[bb * 6 + k] * Ws[k * HID + hh];
#pragma unroll
        for (int k = 0; k < 10; ++k) acc += fs[k] * Ws[(6 + k) * HID + hh];
        h[(size_t)n * BH + idx] = acc;   // normal store: h must stay L2/L3-hot
    }
}

// XCD-pinned aggregation. bid = q*5000 + g*8 + b -> XCD b, quarter q.
// Degree-sorted wave assignment (perm) removes deg-divergence; output stores
// are non-temporal so the write stream doesn't evict the 2.56 MB gather slice.
__global__ __launch_bounds__(256) void aggregate_xcd(const float* __restrict__ hin,
                                                     const int* __restrict__ off,
                                                     const uint16_t* __restrict__ csr,
                                                     const float* __restrict__ dinv,
                                                     const int* __restrict__ perm,
                                                     float* __restrict__ out,
                                                     int final_scatter) {
    int bid = blockIdx.x;
    int b   = bid & 7;                  // batch == XCD
    int q   = bid / 5000;               // quarter 0..3
    int g   = (bid - q * 5000) >> 3;    // node group 0..624
    int tid = threadIdx.x;
    int w = tid >> 6, l = tid & 63;
    int n = perm[g * 32 + w * 8 + (l >> 3)];
    int sub = l & 7;
    int boff = b * 32 + q * 8 + sub;    // float4 index within node's 256-f4 row

    const float4* hp4 = (const float4*)hin;
    float dn = dinv[n];
    float d2 = dn * dn;
    float4 acc = hp4[(size_t)n * 256 + boff];
    acc.x *= d2; acc.y *= d2; acc.z *= d2; acc.w *= d2;

    int s = off[n], e = off[n + 1];
    int p = s;
    for (; p + 2 <= e; p += 2) {
        int s0 = csr[p], s1 = csr[p + 1];
        float w0 = dinv[s0] * dn, w1 = dinv[s1] * dn;
        float4 v0 = hp4[(size_t)s0 * 256 + boff];
        float4 v1 = hp4[(size_t)s1 * 256 + boff];
        acc.x += w0 * v0.x + w1 * v1.x;
        acc.y += w0 * v0.y + w1 * v1.y;
        acc.z += w0 * v0.z + w1 * v1.z;
        acc.w += w0 * v0.w + w1 * v1.w;
    }
    if (p < e) {
        int s0 = csr[p];
        float w0 = dinv[s0] * dn;
        float4 v0 = hp4[(size_t)s0 * 256 + boff];
        acc.x += w0 * v0.x; acc.y += w0 * v0.y;
        acc.z += w0 * v0.z; acc.w += w0 * v0.w;
    }

    size_t o4 = final_scatter ? (((size_t)b * N_NODES + n) * 32 + q * 8 + sub)
                              : ((size_t)n * 256 + boff);
    nt_store4((float*)&((float4*)out)[o4], acc);
}

// In-place row transform: data[r,:] = relu(data[r,:] @ W + bias)
// 256-row tile, 16x8 thread tile: 6 b128 LDS reads per 128 FMAs
// (vs 4 per 64 before) -> LDS-port time cut ~25%.
__global__ __launch_bounds__(256, 2) void gemm_bias_relu(float* data,
                                                         const float* __restrict__ W,
                                                         const float* __restrict__ bias) {
    __shared__ float As_T[32][264];   // [k][row], stride 264 (16B-aligned rows)
    __shared__ float Wls[32][HID];
    int tid = threadIdx.x;
    int rg = tid >> 4;    // rows rg*16 .. rg*16+15
    int cg = tid & 15;    // cols cg*4..+3 and 64+cg*4..+3
    size_t m0 = (size_t)blockIdx.x * 256;
    float acc[16][8] = {};

    for (int kt = 0; kt < HID; kt += 32) {
        __syncthreads();
#pragma unroll
        for (int i = 0; i < 8; ++i) {
            int f = tid + i * 256;          // 0..2047 over 256 rows x 8 float4
            int row = f >> 3;
            int kk = (f & 7) << 2;
            float4 v = *(const float4*)&data[(m0 + row) * HID + kt + kk];
            As_T[kk + 0][row] = v.x;
            As_T[kk + 1][row] = v.y;
            As_T[kk + 2][row] = v.z;
            As_T[kk + 3][row] = v.w;
        }
#pragma unroll
        for (int i = 0; i < 4; ++i) {
            int f = tid + i * 256;          // 0..1023 over 32 rows x 32 float4
            int row = f >> 5;
            int kk = (f & 31) << 2;
            *(float4*)&Wls[row][kk] = *(const float4*)&W[(size_t)(kt + row) * HID + kk];
        }
        __syncthreads();
#pragma unroll 4
        for (int k = 0; k < 32; ++k) {
            float4 w0 = *(const float4*)&Wls[k][cg * 4];
            float4 w1 = *(const float4*)&Wls[k][cg * 4 + 64];
            float wv[8] = {w0.x, w0.y, w0.z, w0.w, w1.x, w1.y, w1.z, w1.w};
#pragma unroll
            for (int ii = 0; ii < 4; ++ii) {
                float4 a = *(const float4*)&As_T[k][rg * 16 + ii * 4];
                float av[4] = {a.x, a.y, a.z, a.w};
#pragma unroll
                for (int r = 0; r < 4; ++r)
#pragma unroll
                    for (int j = 0; j < 8; ++j)
                        acc[ii * 4 + r][j] += av[r] * wv[j];
            }
        }
    }

    float4 b0 = *(const float4*)&bias[cg * 4];
    float4 b1 = *(const float4*)&bias[cg * 4 + 64];
#pragma unroll
    for (int i = 0; i < 16; ++i) {
        size_t r = m0 + rg * 16 + i;
        float4 o0, o1;
        o0.x = fmaxf(acc[i][0] + b0.x, 0.0f);
        o0.y = fmaxf(acc[i][1] + b0.y, 0.0f);
        o0.z = fmaxf(acc[i][2] + b0.z, 0.0f);
        o0.w = fmaxf(acc[i][3] + b0.w, 0.0f);
        o1.x = fmaxf(acc[i][4] + b1.x, 0.0f);
        o1.y = fmaxf(acc[i][5] + b1.y, 0.0f);
        o1.z = fmaxf(acc[i][6] + b1.z, 0.0f);
        o1.w = fmaxf(acc[i][7] + b1.w, 0.0f);
        *(float4*)&data[r * HID + cg * 4] = o0;
        *(float4*)&data[r * HID + cg * 4 + 64] = o1;
    }
}

extern "C" void kernel_launch(void* const* d_in, const int* in_sizes, int n_in,
                              void* d_out, int out_size, void* d_ws, size_t ws_size,
                              hipStream_t stream) {
    const float* x      = (const float*)d_in[0];
    const float* fixedf = (const float*)d_in[1];
    const float* W_in   = (const float*)d_in[2];
    const float* b_in   = (const float*)d_in[3];
    const float* Wg     = (const float*)d_in[4];
    const float* bg     = (const float*)d_in[5];
    const int*   ei     = (const int*)d_in[6];

    const int* rowi = ei;
    const int* coli = ei + N_EDGES;

    char* ws = (char*)d_ws;
    int*      deg    = (int*)(ws + O_DEG);
    int*      cursor = (int*)(ws + O_CUR);
    int*      off    = (int*)(ws + O_OFF);
    float*    dinv   = (float*)(ws + O_DINV);
    uint16_t* csr    = (uint16_t*)(ws + O_CSR);
    int*      perm   = (int*)(ws + O_PERM);
    int*      hist   = (int*)(ws + O_HIST);
    int*      bcur   = (int*)(ws + O_BCUR);
    float*    hA     = (float*)(ws + O_HBUF);
    float*    hB     = (float*)d_out;

    hipMemsetAsync(deg, 0, N_NODES * sizeof(int), stream);
    hipMemsetAsync(cursor, 0, N_NODES * sizeof(int), stream);
    hipMemsetAsync(hist, 0, 64 * sizeof(int), stream);

    count_deg<<<(N_EDGES + 255) / 256, 256, 0, stream>>>(coli, deg);
    compute_dinv<<<(N_NODES + 255) / 256, 256, 0, stream>>>(deg, dinv);
    scan_offsets<<<1, 1024, 0, stream>>>(deg, off);
    fill_csr<<<(N_EDGES + 255) / 256, 256, 0, stream>>>(rowi, coli, off, cursor, csr);
    sort_adj<<<N_NODES, 64, 0, stream>>>(off, csr);
    deg_hist<<<(N_NODES + 255) / 256, 256, 0, stream>>>(deg, hist);
    hist_scan<<<1, 64, 0, stream>>>(hist, bcur);
    build_perm<<<(N_NODES + 255) / 256, 256, 0, stream>>>(deg, bcur, perm);

    input_proj<<<N_NODES, 256, 0, stream>>>(x, fixedf, W_in, b_in, hA);

    const int AB = 4 * 5000;                  // 32 (q,b) passes
    const int GB = (BATCH * N_NODES) / 256;   // 625 gemm blocks

    // L0: hA --agg--> hB(d_out) --gemm in-place--> h1 in hB
    aggregate_xcd<<<AB, 256, 0, stream>>>(hA, off, csr, dinv, perm, hB, 0);
    gemm_bias_relu<<<GB, 256, 0, stream>>>(hB, Wg + 0 * HID * HID, bg + 0 * HID);
    // L1: hB --agg--> hA --gemm in-place--> h2 in hA
    aggregate_xcd<<<AB, 256, 0, stream>>>(hB, off, csr, dinv, perm, hA, 0);
    gemm_bias_relu<<<GB, 256, 0, stream>>>(hA, Wg + 1 * HID * HID, bg + 1 * HID);
    // L2: hA --agg(scatter [b][n])--> d_out --gemm in-place--> final
    aggregate_xcd<<<AB, 256, 0, stream>>>(hA, off, csr, dinv, perm, (float*)d_out, 1);
    gemm_bias_relu<<<GB, 256, 0, stream>>>((float*)d_out, Wg + 2 * HID * HID, bg + 2 * HID);
}

// Round 11
// 637.930 us; speedup vs baseline: 1.4302x; 1.4302x over previous
//
#include <hip/hip_runtime.h>
#include <hip/hip_bf16.h>
#include <cstdint>

#define N_NODES 20000
#define N_EDGES 320000
#define BATCH 8
#define HID 128

// ---------------- workspace layout (bytes) ----------------
static constexpr size_t O_DEG  = 0;
static constexpr size_t O_CUR  = 81920;
static constexpr size_t O_OFF  = 163840;
static constexpr size_t O_DINV = 245760;
static constexpr size_t O_CSR  = 327680;    // 320000 u16 = 640,000 B
static constexpr size_t O_HBUF = 2891776;   // 160000*128 f = 81,920,000 B

// chunked h layout: 32 slices, slice (q,b) = [N_NODES][32 floats], contiguous.
// float4 base of slice (q,b): (q*8+b)*N_NODES*8

__global__ void count_deg(const int* __restrict__ col, int* __restrict__ deg) {
    int e = blockIdx.x * 256 + threadIdx.x;
    if (e < N_EDGES) atomicAdd(&deg[col[e]], 1);
}

__global__ void compute_dinv(const int* __restrict__ deg, float* __restrict__ dinv) {
    int i = blockIdx.x * 256 + threadIdx.x;
    if (i < N_NODES) {
        float d = (float)(deg[i] + 1);   // +1 self loop
        dinv[i] = 1.0f / sqrtf(d);
    }
}

__global__ __launch_bounds__(1024) void scan_offsets(const int* __restrict__ deg,
                                                     int* __restrict__ off) {
    __shared__ int part[1024];
    const int CH = 20;
    int tid = threadIdx.x;
    int base = tid * CH;
    int s = 0;
    for (int i = 0; i < CH; ++i) {
        int idx = base + i;
        if (idx < N_NODES) s += deg[idx];
    }
    part[tid] = s;
    __syncthreads();
    for (int d = 1; d < 1024; d <<= 1) {
        int add = 0;
        if (tid >= d) add = part[tid - d];
        __syncthreads();
        part[tid] += add;
        __syncthreads();
    }
    int run = part[tid] - s;
    for (int i = 0; i < CH; ++i) {
        int idx = base + i;
        if (idx < N_NODES) {
            off[idx] = run;
            run += deg[idx];
        }
    }
    if (tid == 1023) off[N_NODES] = part[1023];
}

__global__ void fill_csr(const int* __restrict__ rowi, const int* __restrict__ coli,
                         const int* __restrict__ off, int* __restrict__ cursor,
                         uint16_t* __restrict__ csr) {
    int e = blockIdx.x * 256 + threadIdx.x;
    if (e >= N_EDGES) return;
    int r = rowi[e], c = coli[e];
    int pos = atomicAdd(&cursor[c], 1);
    csr[off[c] + pos] = (uint16_t)r;
}

// Sort each node's in-edge list by src (deterministic content; locality).
__global__ __launch_bounds__(64) void sort_adj(const int* __restrict__ off,
                                               uint16_t* __restrict__ csr) {
    int n = blockIdx.x;
    int s = off[n], e = off[n + 1];
    int deg = e - s;
    if (deg <= 1 || deg > 64) return;
    int l = threadIdx.x;
    int my = (l < deg) ? (int)csr[s + l] : 0x7fffffff;
    int rank = 0;
    for (int j = 0; j < deg; ++j) {
        int kj = __shfl(my, j);
        rank += (kj < my) || (kj == my && j < l);
    }
    if (l < deg) csr[s + rank] = (uint16_t)my;
}

// h0 = concat(x, fixed) @ W_in + b_in, stored CHUNKED: slice(q,b)[n][k&31]
__global__ __launch_bounds__(256) void input_proj(const float* __restrict__ x,
                                                  const float* __restrict__ fixedf,
                                                  const float* __restrict__ W,
                                                  const float* __restrict__ bvec,
                                                  float* __restrict__ h) {
    __shared__ float Ws[16 * HID];
    __shared__ float xs[BATCH * 6];
    __shared__ float fs[10];
    int n = blockIdx.x, tid = threadIdx.x;
    for (int i = tid; i < 16 * HID; i += 256) Ws[i] = W[i];
    if (tid < 48) {
        int b_ = tid / 6, o = tid % 6;
        xs[tid] = x[((size_t)b_ * N_NODES + n) * 6 + o];
    } else if (tid < 58) {
        fs[tid - 48] = fixedf[(size_t)n * 10 + (tid - 48)];
    }
    __syncthreads();
#pragma unroll
    for (int j = 0; j < 4; ++j) {
        int idx = tid + j * 256;
        int bb = idx >> 7, hh = idx & 127;
        float acc = bvec[hh];
#pragma unroll
        for (int k = 0; k < 6; ++k) acc += xs[bb * 6 + k] * Ws[k * HID + hh];
#pragma unroll
        for (int k = 0; k < 10; ++k) acc += fs[k] * Ws[(6 + k) * HID + hh];
        size_t a = ((size_t)((hh >> 5) * 8 + bb) * N_NODES + n) * 32 + (hh & 31);
        h[a] = acc;
    }
}

// XCD-pinned aggregation on CHUNKED layout. bid = q*5000 + g*8 + b -> XCD b.
// Pass (q,b) reads AND writes one contiguous 2.56 MB slice: sequential
// full-line writes (no write-allocate pollution), gather confined to slice.
__global__ __launch_bounds__(256) void aggregate_xcd(const float* __restrict__ hin,
                                                     const int* __restrict__ off,
                                                     const uint16_t* __restrict__ csr,
                                                     const float* __restrict__ dinv,
                                                     float* __restrict__ out,
                                                     int final_scatter) {
    int bid = blockIdx.x;
    int b   = bid & 7;                  // batch == XCD
    int q   = bid / 5000;               // quarter 0..3
    int g   = (bid - q * 5000) >> 3;    // node group 0..624
    int tid = threadIdx.x;
    int l = tid & 63;
    int n = g * 32 + ((tid >> 6) << 3) + (l >> 3);
    int sub = l & 7;                    // float4 within 32-float chunk
    const size_t SB4 = (size_t)(q * 8 + b) * N_NODES * 8;

    const float4* hp4 = (const float4*)hin;
    float dn = dinv[n];
    float d2 = dn * dn;
    float4 acc = hp4[SB4 + (size_t)n * 8 + sub];
    acc.x *= d2; acc.y *= d2; acc.z *= d2; acc.w *= d2;

    int s = off[n], e = off[n + 1];
    int p = s;
    for (; p + 2 <= e; p += 2) {
        int s0 = csr[p], s1 = csr[p + 1];
        float w0 = dinv[s0] * dn, w1 = dinv[s1] * dn;
        float4 v0 = hp4[SB4 + (size_t)s0 * 8 + sub];
        float4 v1 = hp4[SB4 + (size_t)s1 * 8 + sub];
        acc.x += w0 * v0.x + w1 * v1.x;
        acc.y += w0 * v0.y + w1 * v1.y;
        acc.z += w0 * v0.z + w1 * v1.z;
        acc.w += w0 * v0.w + w1 * v1.w;
    }
    if (p < e) {
        int s0 = csr[p];
        float w0 = dinv[s0] * dn;
        float4 v0 = hp4[SB4 + (size_t)s0 * 8 + sub];
        acc.x += w0 * v0.x; acc.y += w0 * v0.y;
        acc.z += w0 * v0.z; acc.w += w0 * v0.w;
    }

    size_t o4 = final_scatter ? ((size_t)(b * N_NODES + n) * 32 + q * 8 + sub)
                              : (SB4 + (size_t)n * 8 + sub);
    ((float4*)out)[o4] = acc;
}

// Row transform: out[r,:] = relu(in[r,:] @ W + bias), in-place safe per block.
// dense=0: chunked in/out (k-tile 32 == one chunk -> contiguous 16KB A loads).
// dense=1: row-major [b*N+n][128] in/out (final layer).
// Grid: 8 * 157 blocks; rows = (b, n0..n0+127), tail block has 32 valid rows.
__global__ __launch_bounds__(256) void gemm_bias_relu(const float* __restrict__ in,
                                                      float* __restrict__ outp,
                                                      const float* __restrict__ W,
                                                      const float* __restrict__ bias,
                                                      int dense) {
    __shared__ float As_T[32][132];
    __shared__ float Wls[32][HID];
    int tid = threadIdx.x;
    int rg = tid >> 4;    // rows rg*8 .. rg*8+7
    int cg = tid & 15;    // cols cg*4..+3 and 64+cg*4..+3
    int b  = blockIdx.x / 157;
    int n0 = (blockIdx.x % 157) * 128;
    float acc[8][8] = {};
    const float4* in4 = (const float4*)in;

    for (int kt = 0; kt < HID; kt += 32) {
        int q = kt >> 5;
        __syncthreads();
#pragma unroll
        for (int i = 0; i < 4; ++i) {
            int f = tid + i * 256;          // 0..1023 over 128 rows x 8 float4
            int row = f >> 3;
            int kk4 = f & 7;
            int n = n0 + row;
            if (n > N_NODES - 1) n = N_NODES - 1;
            size_t rb4 = dense ? (((size_t)b * N_NODES + n) * 32 + q * 8)
                               : (((size_t)(q * 8 + b) * N_NODES + n) * 8);
            float4 v = in4[rb4 + kk4];
            int kk = kk4 << 2;
            As_T[kk + 0][row] = v.x;
            As_T[kk + 1][row] = v.y;
            As_T[kk + 2][row] = v.z;
            As_T[kk + 3][row] = v.w;
        }
#pragma unroll
        for (int i = 0; i < 4; ++i) {
            int f = tid + i * 256;          // 0..1023 over 32 rows x 32 float4
            int row = f >> 5;
            int kk = (f & 31) << 2;
            *(float4*)&Wls[row][kk] = *(const float4*)&W[(size_t)(kt + row) * HID + kk];
        }
        __syncthreads();
#pragma unroll 8
        for (int k = 0; k < 32; ++k) {
            float4 a0 = *(const float4*)&As_T[k][rg * 8];
            float4 a1 = *(const float4*)&As_T[k][rg * 8 + 4];
            float4 w0 = *(const float4*)&Wls[k][cg * 4];
            float4 w1 = *(const float4*)&Wls[k][cg * 4 + 64];
            float av[8] = {a0.x, a0.y, a0.z, a0.w, a1.x, a1.y, a1.z, a1.w};
            float wv[8] = {w0.x, w0.y, w0.z, w0.w, w1.x, w1.y, w1.z, w1.w};
#pragma unroll
            for (int i = 0; i < 8; ++i)
#pragma unroll
                for (int j = 0; j < 8; ++j)
                    acc[i][j] += av[i] * wv[j];
        }
    }

    float4 b0 = *(const float4*)&bias[cg * 4];
    float4 b1 = *(const float4*)&bias[cg * 4 + 64];
    float4* out4 = (float4*)outp;
#pragma unroll
    for (int i = 0; i < 8; ++i) {
        int n = n0 + rg * 8 + i;
        if (n >= N_NODES) break;
        float4 o0, o1;
        o0.x = fmaxf(acc[i][0] + b0.x, 0.0f);
        o0.y = fmaxf(acc[i][1] + b0.y, 0.0f);
        o0.z = fmaxf(acc[i][2] + b0.z, 0.0f);
        o0.w = fmaxf(acc[i][3] + b0.w, 0.0f);
        o1.x = fmaxf(acc[i][4] + b1.x, 0.0f);
        o1.y = fmaxf(acc[i][5] + b1.y, 0.0f);
        o1.z = fmaxf(acc[i][6] + b1.z, 0.0f);
        o1.w = fmaxf(acc[i][7] + b1.w, 0.0f);
        if (dense) {
            size_t r4 = ((size_t)b * N_NODES + n) * 32;
            out4[r4 + cg] = o0;
            out4[r4 + cg + 16] = o1;
        } else {
            int q0 = cg >> 3, f0 = cg & 7;
            out4[((size_t)(q0 * 8 + b) * N_NODES + n) * 8 + f0] = o0;
            out4[((size_t)((q0 + 2) * 8 + b) * N_NODES + n) * 8 + f0] = o1;
        }
    }
}

extern "C" void kernel_launch(void* const* d_in, const int* in_sizes, int n_in,
                              void* d_out, int out_size, void* d_ws, size_t ws_size,
                              hipStream_t stream) {
    const float* x      = (const float*)d_in[0];
    const float* fixedf = (const float*)d_in[1];
    const float* W_in   = (const float*)d_in[2];
    const float* b_in   = (const float*)d_in[3];
    const float* Wg     = (const float*)d_in[4];
    const float* bg     = (const float*)d_in[5];
    const int*   ei     = (const int*)d_in[6];

    const int* rowi = ei;
    const int* coli = ei + N_EDGES;

    char* ws = (char*)d_ws;
    int*      deg    = (int*)(ws + O_DEG);
    int*      cursor = (int*)(ws + O_CUR);
    int*      off    = (int*)(ws + O_OFF);
    float*    dinv   = (float*)(ws + O_DINV);
    uint16_t* csr    = (uint16_t*)(ws + O_CSR);
    float*    hA     = (float*)(ws + O_HBUF);   // chunked
    float*    hB     = (float*)d_out;           // chunked intermediate / final dense

    hipMemsetAsync(deg, 0, N_NODES * sizeof(int), stream);
    hipMemsetAsync(cursor, 0, N_NODES * sizeof(int), stream);

    count_deg<<<(N_EDGES + 255) / 256, 256, 0, stream>>>(coli, deg);
    compute_dinv<<<(N_NODES + 255) / 256, 256, 0, stream>>>(deg, dinv);
    scan_offsets<<<1, 1024, 0, stream>>>(deg, off);
    fill_csr<<<(N_EDGES + 255) / 256, 256, 0, stream>>>(rowi, coli, off, cursor, csr);
    sort_adj<<<N_NODES, 64, 0, stream>>>(off, csr);

    input_proj<<<N_NODES, 256, 0, stream>>>(x, fixedf, W_in, b_in, hA);

    const int AB = 4 * 5000;    // 32 (q,b) passes
    const int GB = 8 * 157;     // per-batch row blocks (tail block: 32 rows)

    // L0: hA --agg--> hB (chunked) --gemm in-place (chunked)-->
    aggregate_xcd<<<AB, 256, 0, stream>>>(hA, off, csr, dinv, hB, 0);
    gemm_bias_relu<<<GB, 256, 0, stream>>>(hB, hB, Wg + 0 * HID * HID, bg + 0 * HID, 0);
    // L1: hB --agg--> hA (chunked) --gemm in-place (chunked)-->
    aggregate_xcd<<<AB, 256, 0, stream>>>(hB, off, csr, dinv, hA, 0);
    gemm_bias_relu<<<GB, 256, 0, stream>>>(hA, hA, Wg + 1 * HID * HID, bg + 1 * HID, 0);
    // L2: hA --agg(scatter dense [b][n][h])--> d_out --gemm in-place (dense)-->
    aggregate_xcd<<<AB, 256, 0, stream>>>(hA, off, csr, dinv, (float*)d_out, 1);
    gemm_bias_relu<<<GB, 256, 0, stream>>>((float*)d_out, (float*)d_out,
                                           Wg + 2 * HID * HID, bg + 2 * HID, 1);
}